// Round 19
// baseline (341.736 us; speedup 1.0000x reference)
//
#include <hip/hip_runtime.h>
#include <hip/hip_bf16.h>

#define NN 384
#define CZ 128
#define NH 4
#define NROWS (NN*NN)
#define LN_EPS 1e-5f
#define LOG2E 1.4426950408889634f
#define QSCALE_L2 (0.17677669529663687f * 1.4426950408889634f)  // 1/sqrt(32) * log2(e)

typedef unsigned short u16;
typedef unsigned int   u32;
typedef __attribute__((ext_vector_type(8))) __bf16 bf16x8;
typedef __attribute__((ext_vector_type(16))) float f32x16;
typedef __attribute__((ext_vector_type(2))) float f32x2;

__device__ __forceinline__ float bflo(u32 u) { union { u32 i; float f; } a; a.i = u << 16; return a.f; }
__device__ __forceinline__ float bfhi(u32 u) { union { u32 i; float f; } a; a.i = u & 0xffff0000u; return a.f; }
__device__ __forceinline__ u16 f2bf(float f) {
  union { float f; u32 i; } a; a.f = f;
  u32 r = a.i + 0x7fffu + ((a.i >> 16) & 1u);
  return (u16)(r >> 16);
}
__device__ __forceinline__ u32 cvtpk(float lo, float hi) {
  u32 r; asm("v_cvt_pk_bf16_f32 %0, %1, %2" : "=v"(r) : "v"(lo), "v"(hi)); return r;
}
__device__ __forceinline__ float exp2fast(float x) {
  float r; asm("v_exp_f32 %0, %1" : "=v"(r) : "v"(x)); return r;
}
__device__ __forceinline__ float sigm(float x) {
  return 1.f / (1.f + exp2fast(-x * LOG2E));
}
__device__ __forceinline__ f32x2 pkadd(f32x2 a, f32x2 b) {
  f32x2 d; asm("v_pk_add_f32 %0, %1, %2" : "=v"(d) : "v"(a), "v"(b)); return d;
}

// ---------------- Kernel 0: one-time weight convert + swizzle --------------
__global__ __launch_bounds__(256) void k_wcvt(const float* __restrict__ wq,
    const float* __restrict__ wk, const float* __restrict__ wv,
    const float* __restrict__ wg, const float* __restrict__ wo,
    u16* __restrict__ wsw) {
  int m = blockIdx.x;
  const float* W = (m == 0) ? wq : (m == 1) ? wk : (m == 2) ? wv : (m == 3) ? wg : wo;
  float sc = (m == 0) ? QSCALE_L2 : 1.f;
  u16* dst = wsw + (size_t)m * 16384;
  for (int idx = threadIdx.x; idx < 2048; idx += 256) {
    int e = idx >> 4, s = idx & 15;
    float4 f0 = *(const float4*)&W[e * CZ + s * 8];
    float4 f1 = *(const float4*)&W[e * CZ + s * 8 + 4];
    uint4 st;
    st.x = cvtpk(f0.x * sc, f0.y * sc); st.y = cvtpk(f0.z * sc, f0.w * sc);
    st.z = cvtpk(f1.x * sc, f1.y * sc); st.w = cvtpk(f1.z * sc, f1.w * sc);
    *(uint4*)&dst[e * CZ + (s ^ (e & 15)) * 8] = st;
  }
}

// ---------------- Kernel 1: FUSED LayerNorm + projections ------------------
// Block = 128 rows. Phase A: LN into swizzled LDS x tile (+ pb to global).
// Phase B: 4 sequential GEMMs (wl restaged per mat from wsw); v transposed
// through wl-as-tb (xl preserved for m=3).
__global__ __launch_bounds__(256) void k_lnp(const float* __restrict__ act,
    const float* __restrict__ lnw, const float* __restrict__ lnb,
    const float* __restrict__ w2d, u16* __restrict__ pbF,
    const u16* __restrict__ wsw, const float* __restrict__ bg,
    u16* __restrict__ qb, u16* __restrict__ kb,
    u16* __restrict__ vT, u16* __restrict__ gb) {
  __shared__ __align__(16) u16 xl[128][128];  // 32 KB
  __shared__ __align__(16) u16 wl[128][128];  // 32 KB
  int t = threadIdx.x;
  int lane = t & 63, wid = t >> 6;
  int jl = lane & 31, g = lane >> 5;
  size_t row0 = (size_t)blockIdx.x * 128;

  // ---- Phase A: LayerNorm (k_ln body, LDS destination) ----
  {
    int l32 = t & 31;
    int rb = t >> 5;  // 0..7
    #pragma unroll 2
    for (int it = 0; it < 16; ++it) {
      int rloc = it * 8 + rb;
      size_t r = row0 + rloc;
      const float4 a = *(const float4*)(act + r * CZ + l32 * 4);
      float s = (a.x + a.y) + (a.z + a.w);
      float s2 = (a.x * a.x + a.y * a.y) + (a.z * a.z + a.w * a.w);
      #pragma unroll
      for (int m = 16; m >= 1; m >>= 1) { s += __shfl_xor(s, m, 32); s2 += __shfl_xor(s2, m, 32); }
      float mu = s * (1.0f / CZ);
      float inv = rsqrtf(s2 * (1.0f / CZ) - mu * mu + LN_EPS);
      float4 w = *(const float4*)(lnw + l32 * 4);
      float4 b = *(const float4*)(lnb + l32 * 4);
      float4 xv;
      xv.x = (a.x - mu) * inv * w.x + b.x;
      xv.y = (a.y - mu) * inv * w.y + b.y;
      xv.z = (a.z - mu) * inv * w.z + b.z;
      xv.w = (a.w - mu) * inv * w.w + b.w;
      uint2 st; st.x = cvtpk(xv.x, xv.y); st.y = cvtpk(xv.z, xv.w);
      int scol = ((l32 >> 1) ^ (rloc & 15)) * 8 + (l32 & 1) * 4;
      *(uint2*)&xl[rloc][scol] = st;
      int j = (int)(r / NN), k = (int)(r - (size_t)j * NN);
      int t32 = k >> 5, kl = k & 31;
      int gg = (kl >> 2) & 1, rr2 = (kl & 3) + 4 * (kl >> 3);
      size_t pidx = (size_t)t32 * 12288 + (size_t)j * 32 + gg * 16 + rr2;
      #pragma unroll
      for (int h = 0; h < NH; ++h) {
        float4 wd = *(const float4*)(w2d + h * CZ + l32 * 4);
        float p = (xv.x * wd.x + xv.y * wd.y) + (xv.z * wd.z + xv.w * wd.w);
        #pragma unroll
        for (int m = 16; m >= 1; m >>= 1) p += __shfl_xor(p, m, 32);
        if (l32 == 0) pbF[(size_t)h * NROWS + pidx] = f2bf(p * LOG2E);
      }
    }
  }
  __syncthreads();

  // ---- Phase B: 4 GEMMs ----
  int rf = (wid & 1) * 64, ef = (wid >> 1) * 64;
  for (int m = 0; m < 4; ++m) {
    {
      const uint4* wsrc = (const uint4*)(wsw + (size_t)m * 16384);
      uint4* wd = (uint4*)wl;
      #pragma unroll
      for (int p = 0; p < 8; ++p) wd[t + p * 256] = wsrc[t + p * 256];
    }
    __syncthreads();
    f32x16 acc[2][2];
    #pragma unroll
    for (int a = 0; a < 2; ++a)
      #pragma unroll
      for (int b = 0; b < 2; ++b)
        #pragma unroll
        for (int i = 0; i < 16; ++i) acc[a][b][i] = 0.f;
    #pragma unroll
    for (int ks = 0; ks < 8; ++ks) {
      bf16x8 xa[2], wf[2];
      #pragma unroll
      for (int a = 0; a < 2; ++a) {
        int r = rf + a * 32 + jl;
        xa[a] = *(const bf16x8*)&xl[r][((2 * ks + g) ^ (r & 15)) * 8];
      }
      #pragma unroll
      for (int b = 0; b < 2; ++b) {
        int e = ef + b * 32 + jl;
        wf[b] = *(const bf16x8*)&wl[e][((2 * ks + g) ^ (e & 15)) * 8];
      }
      if (m == 2) {
        #pragma unroll
        for (int a = 0; a < 2; ++a)
          #pragma unroll
          for (int b = 0; b < 2; ++b)
            acc[a][b] = __builtin_amdgcn_mfma_f32_32x32x16_bf16(xa[a], wf[b], acc[a][b], 0, 0, 0);
      } else {
        #pragma unroll
        for (int a = 0; a < 2; ++a)
          #pragma unroll
          for (int b = 0; b < 2; ++b)
            acc[a][b] = __builtin_amdgcn_mfma_f32_32x32x16_bf16(wf[b], xa[a], acc[a][b], 0, 0, 0);
      }
    }

    if (m == 2) {  // v: transpose through wl-as-tb (xl preserved)
      __syncthreads();  // all waves done reading wl (and xl this phase)
      u32* tb = (u32*)wl;
      #pragma unroll
      for (int half = 0; half < 2; ++half) {
        if ((wid >> 1) == half) {
          #pragma unroll
          for (int a = 0; a < 2; ++a)
            #pragma unroll
            for (int b = 0; b < 2; ++b) {
              int e_loc = b * 32 + jl;
              #pragma unroll
              for (int rr = 0; rr < 4; ++rr) {
                int tok = rf + a * 32 + 8 * rr + 4 * g;
                tb[e_loc * 65 + (tok >> 1)]     = cvtpk(acc[a][b][4 * rr + 0], acc[a][b][4 * rr + 1]);
                tb[e_loc * 65 + (tok >> 1) + 1] = cvtpk(acc[a][b][4 * rr + 2], acc[a][b][4 * rr + 3]);
              }
            }
        }
        __syncthreads();
        #pragma unroll
        for (int it = 0; it < 4; ++it) {
          int idx = t + it * 256;
          int e_loc = idx >> 4, cc = idx & 15;
          uint4 st;
          st.x = tb[e_loc * 65 + cc * 4 + 0];
          st.y = tb[e_loc * 65 + cc * 4 + 1];
          st.z = tb[e_loc * 65 + cc * 4 + 2];
          st.w = tb[e_loc * 65 + cc * 4 + 3];
          *(uint4*)&vT[(size_t)(half * 64 + e_loc) * NROWS + row0 + cc * 8] = st;
        }
        __syncthreads();
      }
    } else {  // q/k/g: row-major store
      u16* ob = (m == 0) ? qb : (m == 1) ? kb : gb;
      #pragma unroll
      for (int a = 0; a < 2; ++a) {
        size_t row = row0 + rf + a * 32 + jl;
        #pragma unroll
        for (int b = 0; b < 2; ++b) {
          u16* dst = ob + row * CZ + ef + b * 32 + 4 * g;
          #pragma unroll
          for (int rr = 0; rr < 4; ++rr) {
            float v0 = acc[a][b][4 * rr + 0], v1 = acc[a][b][4 * rr + 1];
            float v2 = acc[a][b][4 * rr + 2], v3 = acc[a][b][4 * rr + 3];
            if (m == 3) {
              float4 bv = *(const float4*)&bg[ef + b * 32 + 8 * rr + 4 * g];
              v0 = sigm(v0 + bv.x); v1 = sigm(v1 + bv.y);
              v2 = sigm(v2 + bv.z); v3 = sigm(v3 + bv.w);
            }
            uint2 st; st.x = cvtpk(v0, v1); st.y = cvtpk(v2, v3);
            *(uint2*)(dst + 8 * rr) = st;
          }
        }
      }
      __syncthreads();  // done reading wl before next mat restages
    }
  }
}

// ---------------- Kernel 3: MFMA attention (unchanged from R18) ------------
template<bool MASKED>
__device__ __forceinline__ void attn_core(const u16* ks, const u16* vs,
    const u16* pbw, const float* mrow4, int jl, int g,
    bf16x8 qf0, bf16x8 qf1, f32x16& oacc, float& lrun,
    uint4 pbA0, uint4 pbA1, uint4 pbA2, uint4 pbA3) {
  uint4 pbB0, pbB1, pbB2, pbB3;

#define ATTN_STEP(CUR, NXT, KT)                                                \
  {                                                                            \
    const int k0 = (KT) * 64;                                                  \
    const int k1 = k0 + 32;                                                    \
    if ((KT) + 1 < 6) {                                                        \
      pb##NXT##0 = *(const uint4*)(pbw + (size_t)(2 * ((KT) + 1)) * 12288);    \
      pb##NXT##1 = *(const uint4*)(pbw + (size_t)(2 * ((KT) + 1)) * 12288 + 8);\
      pb##NXT##2 = *(const uint4*)(pbw + (size_t)(2 * ((KT) + 1) + 1) * 12288);\
      pb##NXT##3 = *(const uint4*)(pbw + (size_t)(2 * ((KT) + 1) + 1) * 12288 + 8);\
    }                                                                          \
    bf16x8 ka0a = *(const bf16x8*)&ks[(k0 + jl) * 40 + 8 * g];                 \
    bf16x8 ka1a = *(const bf16x8*)&ks[(k0 + jl) * 40 + 8 * g + 16];            \
    bf16x8 ka0b = *(const bf16x8*)&ks[(k1 + jl) * 40 + 8 * g];                 \
    bf16x8 ka1b = *(const bf16x8*)&ks[(k1 + jl) * 40 + 8 * g + 16];            \
    bf16x8 va0a = *(const bf16x8*)&vs[jl * 392 + k0 + 8 * g];                  \
    bf16x8 va1a = *(const bf16x8*)&vs[jl * 392 + k0 + 16 + 8 * g];             \
    bf16x8 va0b = *(const bf16x8*)&vs[jl * 392 + k1 + 8 * g];                  \
    bf16x8 va1b = *(const bf16x8*)&vs[jl * 392 + k1 + 16 + 8 * g];             \
    float pva[16], pvb[16];                                                    \
    pva[0]=bflo((pb##CUR##0).x); pva[1]=bfhi((pb##CUR##0).x);                  \
    pva[2]=bflo((pb##CUR##0).y); pva[3]=bfhi((pb##CUR##0).y);                  \
    pva[4]=bflo((pb##CUR##0).z); pva[5]=bfhi((pb##CUR##0).z);                  \
    pva[6]=bflo((pb##CUR##0).w); pva[7]=bfhi((pb##CUR##0).w);                  \
    pva[8]=bflo((pb##CUR##1).x); pva[9]=bfhi((pb##CUR##1).x);                  \
    pva[10]=bflo((pb##CUR##1).y); pva[11]=bfhi((pb##CUR##1).y);                \
    pva[12]=bflo((pb##CUR##1).z); pva[13]=bfhi((pb##CUR##1).z);                \
    pva[14]=bflo((pb##CUR##1).w); pva[15]=bfhi((pb##CUR##1).w);                \
    pvb[0]=bflo((pb##CUR##2).x); pvb[1]=bfhi((pb##CUR##2).x);                  \
    pvb[2]=bflo((pb##CUR##2).y); pvb[3]=bfhi((pb##CUR##2).y);                  \
    pvb[4]=bflo((pb##CUR##2).z); pvb[5]=bfhi((pb##CUR##2).z);                  \
    pvb[6]=bflo((pb##CUR##2).w); pvb[7]=bfhi((pb##CUR##2).w);                  \
    pvb[8]=bflo((pb##CUR##3).x); pvb[9]=bfhi((pb##CUR##3).x);                  \
    pvb[10]=bflo((pb##CUR##3).y); pvb[11]=bfhi((pb##CUR##3).y);                \
    pvb[12]=bflo((pb##CUR##3).z); pvb[13]=bfhi((pb##CUR##3).z);                \
    pvb[14]=bflo((pb##CUR##3).w); pvb[15]=bfhi((pb##CUR##3).w);                \
    f32x16 sacA, sacB;                                                         \
    _Pragma("unroll")                                                          \
    for (int r = 0; r < 16; ++r) { sacA[r] = 0.f; sacB[r] = 0.f; }             \
    __builtin_amdgcn_s_setprio(1);                                             \
    sacA = __builtin_amdgcn_mfma_f32_32x32x16_bf16(ka0a, qf0, sacA, 0, 0, 0);  \
    sacB = __builtin_amdgcn_mfma_f32_32x32x16_bf16(ka0b, qf0, sacB, 0, 0, 0);  \
    sacA = __builtin_amdgcn_mfma_f32_32x32x16_bf16(ka1a, qf1, sacA, 0, 0, 0);  \
    sacB = __builtin_amdgcn_mfma_f32_32x32x16_bf16(ka1b, qf1, sacB, 0, 0, 0);  \
    __builtin_amdgcn_s_setprio(0);                                             \
    f32x2 sa[8], sb[8];                                                        \
    _Pragma("unroll")                                                          \
    for (int rr = 0; rr < 4; ++rr) {                                           \
      sa[2 * rr + 0] = pkadd(f32x2{sacA[4 * rr + 0], sacA[4 * rr + 1]},        \
                             f32x2{pva[4 * rr + 0], pva[4 * rr + 1]});         \
      sa[2 * rr + 1] = pkadd(f32x2{sacA[4 * rr + 2], sacA[4 * rr + 3]},        \
                             f32x2{pva[4 * rr + 2], pva[4 * rr + 3]});         \
      sb[2 * rr + 0] = pkadd(f32x2{sacB[4 * rr + 0], sacB[4 * rr + 1]},        \
                             f32x2{pvb[4 * rr + 0], pvb[4 * rr + 1]});         \
      sb[2 * rr + 1] = pkadd(f32x2{sacB[4 * rr + 2], sacB[4 * rr + 3]},        \
                             f32x2{pvb[4 * rr + 2], pvb[4 * rr + 3]});         \
    }                                                                          \
    if (MASKED) {                                                              \
      _Pragma("unroll")                                                        \
      for (int m4 = 0; m4 < 4; ++m4) {                                         \
        float4 ma = *(const float4*)(mrow4 + k0 + 8 * m4);                     \
        float4 mb = *(const float4*)(mrow4 + k1 + 8 * m4);                     \
        sa[2 * m4 + 0] = pkadd(sa[2 * m4 + 0],                                 \
            f32x2{(ma.x - 1.f) * (1e9f * LOG2E), (ma.y - 1.f) * (1e9f * LOG2E)});\
        sa[2 * m4 + 1] = pkadd(sa[2 * m4 + 1],                                 \
            f32x2{(ma.z - 1.f) * (1e9f * LOG2E), (ma.w - 1.f) * (1e9f * LOG2E)});\
        sb[2 * m4 + 0] = pkadd(sb[2 * m4 + 0],                                 \
            f32x2{(mb.x - 1.f) * (1e9f * LOG2E), (mb.y - 1.f) * (1e9f * LOG2E)});\
        sb[2 * m4 + 1] = pkadd(sb[2 * m4 + 1],                                 \
            f32x2{(mb.z - 1.f) * (1e9f * LOG2E), (mb.w - 1.f) * (1e9f * LOG2E)});\
      }                                                                        \
    }                                                                          \
    f32x2 p2a[8], p2b[8];                                                      \
    _Pragma("unroll")                                                          \
    for (int p8 = 0; p8 < 8; ++p8) {                                           \
      p2a[p8] = f32x2{exp2fast(sa[p8][0]), exp2fast(sa[p8][1])};               \
      p2b[p8] = f32x2{exp2fast(sb[p8][0]), exp2fast(sb[p8][1])};               \
    }                                                                          \
    f32x2 qa0 = pkadd(pkadd(p2a[0], p2a[1]), pkadd(p2a[2], p2a[3]));           \
    f32x2 qa1 = pkadd(pkadd(p2a[4], p2a[5]), pkadd(p2a[6], p2a[7]));           \
    f32x2 qb0 = pkadd(pkadd(p2b[0], p2b[1]), pkadd(p2b[2], p2b[3]));           \
    f32x2 qb1 = pkadd(pkadd(p2b[4], p2b[5]), pkadd(p2b[6], p2b[7]));           \
    f32x2 qt = pkadd(pkadd(qa0, qa1), pkadd(qb0, qb1));                        \
    lrun += qt[0] + qt[1];                                                     \
    u32 Aa = cvtpk(p2a[0][0], p2a[0][1]), Ab = cvtpk(p2a[1][0], p2a[1][1]);    \
    u32 Ba = cvtpk(p2a[2][0], p2a[2][1]), Bb = cvtpk(p2a[3][0], p2a[3][1]);    \
    u32 Ca = cvtpk(p2a[4][0], p2a[4][1]), Cb = cvtpk(p2a[5][0], p2a[5][1]);    \
    u32 Da = cvtpk(p2a[6][0], p2a[6][1]), Db = cvtpk(p2a[7][0], p2a[7][1]);    \
    u32 Ea = cvtpk(p2b[0][0], p2b[0][1]), Eb = cvtpk(p2b[1][0], p2b[1][1]);    \
    u32 Fa = cvtpk(p2b[2][0], p2b[2][1]), Fb = cvtpk(p2b[3][0], p2b[3][1]);    \
    u32 Ga = cvtpk(p2b[4][0], p2b[4][1]), Gb = cvtpk(p2b[5][0], p2b[5][1]);    \
    u32 Ha = cvtpk(p2b[6][0], p2b[6][1]), Hb = cvtpk(p2b[7][0], p2b[7][1]);    \
    auto r0 = __builtin_amdgcn_permlane32_swap(Aa, Ba, false, false);          \
    auto r1 = __builtin_amdgcn_permlane32_swap(Ab, Bb, false, false);          \
    auto r2 = __builtin_amdgcn_permlane32_swap(Ca, Da, false, false);          \
    auto r3 = __builtin_amdgcn_permlane32_swap(Cb, Db, false, false);          \
    auto r4 = __builtin_amdgcn_permlane32_swap(Ea, Fa, false, false);          \
    auto r5 = __builtin_amdgcn_permlane32_swap(Eb, Fb, false, false);          \
    auto r6 = __builtin_amdgcn_permlane32_swap(Ga, Ha, false, false);          \
    auto r7 = __builtin_amdgcn_permlane32_swap(Gb, Hb, false, false);          \
    union { u32 w[4]; bf16x8 v; } b0, b1, b2, b3;                              \
    b0.w[0] = r0[0]; b0.w[1] = r1[0]; b0.w[2] = r0[1]; b0.w[3] = r1[1];        \
    b1.w[0] = r2[0]; b1.w[1] = r3[0]; b1.w[2] = r2[1]; b1.w[3] = r3[1];        \
    b2.w[0] = r4[0]; b2.w[1] = r5[0]; b2.w[2] = r4[1]; b2.w[3] = r5[1];        \
    b3.w[0] = r6[0]; b3.w[1] = r7[0]; b3.w[2] = r6[1]; b3.w[3] = r7[1];        \
    __builtin_amdgcn_s_setprio(1);                                             \
    oacc = __builtin_amdgcn_mfma_f32_32x32x16_bf16(va0a, b0.v, oacc, 0, 0, 0); \
    oacc = __builtin_amdgcn_mfma_f32_32x32x16_bf16(va1a, b1.v, oacc, 0, 0, 0); \
    oacc = __builtin_amdgcn_mfma_f32_32x32x16_bf16(va0b, b2.v, oacc, 0, 0, 0); \
    oacc = __builtin_amdgcn_mfma_f32_32x32x16_bf16(va1b, b3.v, oacc, 0, 0, 0); \
    __builtin_amdgcn_s_setprio(0);                                             \
  }

  ATTN_STEP(A, B, 0); ATTN_STEP(B, A, 1); ATTN_STEP(A, B, 2);
  ATTN_STEP(B, A, 3); ATTN_STEP(A, B, 4); ATTN_STEP(B, A, 5);
#undef ATTN_STEP
}

__global__ __launch_bounds__(768) void k_attn(const u16* __restrict__ q,
    const u16* __restrict__ kmat, const u16* __restrict__ vT,
    const u16* __restrict__ pbF, const float* __restrict__ mask,
    const u16* __restrict__ gmat, u16* __restrict__ o) {
  __shared__ __align__(16) u16 ks[384 * 40];  // K rows padded to 40 bf16
  __shared__ __align__(16) u16 vs[32 * 392];  // V^T rows padded to 392 bf16
  int i = blockIdx.x, h = blockIdx.y;
  int t = threadIdx.x;
  int lane = t & 63, wid = t >> 6;  // wid 0..11
  int jl = lane & 31, g = lane >> 5;
  int j = wid * 32 + jl;
  size_t base = ((size_t)i * NN) * CZ + h * 32;
  const u16* pbw = pbF + (size_t)h * NROWS + (size_t)j * 32 + g * 16;
  uint4 pbA0 = *(const uint4*)(pbw);
  uint4 pbA1 = *(const uint4*)(pbw + 8);
  uint4 pbA2 = *(const uint4*)(pbw + 12288);
  uint4 pbA3 = *(const uint4*)(pbw + 12288 + 8);
  const u16* qp = q + base + (size_t)j * CZ + g * 8;
  bf16x8 qf0 = *(const bf16x8*)qp;
  bf16x8 qf1 = *(const bf16x8*)(qp + 16);
  {
    const u16* src = kmat + base;
    for (int idx = t; idx < 1536; idx += 768) {
      int row = idx >> 2, c = idx & 3;
      *(uint4*)&ks[row * 40 + c * 8] = *(const uint4*)(src + (size_t)row * CZ + c * 8);
    }
    const u16* vsrc = vT + (size_t)(h * 32) * NROWS + (size_t)i * NN;
    for (int idx = t; idx < 1536; idx += 768) {
      int d = idx / 48, c = idx % 48;
      *(uint4*)&vs[d * 392 + c * 8] = *(const uint4*)(vsrc + (size_t)d * NROWS + c * 8);
    }
  }
  const float* mrow = mask + (size_t)i * NN;
  bool m1 = true;
  #pragma unroll
  for (int c = 0; c < 6; ++c) m1 &= (mrow[lane + 64 * c] == 1.f);
  bool nomask = __all(m1);
  __syncthreads();

  f32x16 oacc;
  #pragma unroll
  for (int r = 0; r < 16; ++r) oacc[r] = 0.f;
  float lrun = 0.f;
  if (nomask) attn_core<false>(ks, vs, pbw, mrow + 4 * g, jl, g, qf0, qf1, oacc, lrun,
                               pbA0, pbA1, pbA2, pbA3);
  else        attn_core<true >(ks, vs, pbw, mrow + 4 * g, jl, g, qf0, qf1, oacc, lrun,
                               pbA0, pbA1, pbA2, pbA3);

  float lt = lrun + __shfl_xor(lrun, 32, 64);
  float inv = 1.f / lt;
  const u16* gp = gmat + (size_t)(i * NN + j) * CZ + h * 32 + 4 * g;
  u16* dst = o + (size_t)(i * NN + j) * CZ + h * 32 + 4 * g;
  #pragma unroll
  for (int q4 = 0; q4 < 4; ++q4) {
    uint2 gu = *(const uint2*)(gp + 8 * q4);
    uint2 st;
    st.x = cvtpk(oacc[4 * q4 + 0] * inv * bflo(gu.x), oacc[4 * q4 + 1] * inv * bfhi(gu.x));
    st.y = cvtpk(oacc[4 * q4 + 2] * inv * bflo(gu.y), oacc[4 * q4 + 3] * inv * bfhi(gu.y));
    *(uint2*)(dst + 8 * q4) = st;
  }
}

// ---------------- Kernel 4: MFMA out = t @ wo^T + bo  (fp32 out) -----------
__global__ __launch_bounds__(256) void k_out(const u16* __restrict__ tin,
    const u16* __restrict__ wsw, const float* __restrict__ bo,
    float* __restrict__ out) {
  __shared__ __align__(16) u16 wols[128][128];  // 32 KB
  __shared__ __align__(16) u16 tls[128][128];   // 32 KB
  int t = threadIdx.x;
  int lane = t & 63, wid = t >> 6, jl = lane & 31, gg = lane >> 5;
  size_t row0 = (size_t)blockIdx.x * 128;
  {
    const uint4* wsrc = (const uint4*)(wsw + (size_t)4 * 16384);  // wo slot
    uint4* wd = (uint4*)wols;
    #pragma unroll
    for (int p = 0; p < 8; ++p) wd[t + p * 256] = wsrc[t + p * 256];
  }
  #pragma unroll
  for (int it = 0; it < 8; ++it) {
    int idx = t + it * 256; int r = idx >> 4, s = idx & 15;
    uint4 uo = *(const uint4*)(tin + (row0 + r) * CZ + s * 8);
    *(uint4*)&tls[r][(s ^ (r & 15)) * 8] = uo;
  }
  __syncthreads();
  f32x16 acc[4];
  #pragma unroll
  for (int cf = 0; cf < 4; ++cf)
    #pragma unroll
    for (int i = 0; i < 16; ++i) acc[cf][i] = 0.f;
  #pragma unroll
  for (int ks = 0; ks < 8; ++ks) {
    int r = wid * 32 + jl;
    bf16x8 tf = *(const bf16x8*)&tls[r][((2 * ks + gg) ^ (r & 15)) * 8];
    #pragma unroll
    for (int cf = 0; cf < 4; ++cf) {
      int c = cf * 32 + jl;
      bf16x8 wf = *(const bf16x8*)&wols[c][((2 * ks + gg) ^ (c & 15)) * 8];
      acc[cf] = __builtin_amdgcn_mfma_f32_32x32x16_bf16(wf, tf, acc[cf], 0, 0, 0);
    }
  }
  size_t row = row0 + wid * 32 + jl;
  #pragma unroll
  for (int cf = 0; cf < 4; ++cf)
    #pragma unroll
    for (int rr = 0; rr < 4; ++rr) {
      int c = cf * 32 + 8 * rr + 4 * gg;
      float4 bv = *(const float4*)&bo[c];
      float4 v;
      v.x = acc[cf][4 * rr + 0] + bv.x; v.y = acc[cf][4 * rr + 1] + bv.y;
      v.z = acc[cf][4 * rr + 2] + bv.z; v.w = acc[cf][4 * rr + 3] + bv.w;
      *(float4*)&out[row * CZ + c] = v;
    }
}

extern "C" void kernel_launch(void* const* d_in, const int* in_sizes, int n_in,
                              void* d_out, int out_size, void* d_ws, size_t ws_size,
                              hipStream_t stream) {
  const float* act  = (const float*)d_in[0];
  const float* mask = (const float*)d_in[1];
  const float* ln_w = (const float*)d_in[2];
  const float* ln_b = (const float*)d_in[3];
  const float* w2d  = (const float*)d_in[4];
  const float* wq   = (const float*)d_in[5];
  const float* wk   = (const float*)d_in[6];
  const float* wv   = (const float*)d_in[7];
  const float* wg   = (const float*)d_in[8];
  const float* bg   = (const float*)d_in[9];
  const float* wo   = (const float*)d_in[10];
  const float* bo   = (const float*)d_in[11];
  float* out = (float*)d_out;

  char* ws = (char*)d_ws;
  const size_t sz = (size_t)NROWS * CZ * 2;
  u16* qb  = (u16*)(ws + 1 * sz);
  u16* kb  = (u16*)(ws + 2 * sz);
  u16* vTb = (u16*)(ws + 3 * sz);
  u16* gb  = (u16*)(ws + 4 * sz);
  u16* ob  = (u16*)(ws + 5 * sz);   // holds t = (o/l)*g after k_attn
  u16* pbf = (u16*)(ws + 6 * sz);   // NH*NROWS u16 = 1.18 MB
  u16* wsw = (u16*)(ws + 6 * sz + (2 << 20));  // 5 x 32 KB

  k_wcvt<<<5, 256, 0, stream>>>(wq, wk, wv, wg, wo, wsw);
  k_lnp<<<NROWS / 128, 256, 0, stream>>>(act, ln_w, ln_b, w2d, pbf, wsw, bg,
                                          qb, kb, vTb, gb);
  dim3 ga(NN, NH);
  k_attn<<<ga, 768, 0, stream>>>(qb, kb, vTb, pbf, mask, gb, ob);
  k_out<<<NROWS / 128, 256, 0, stream>>>(ob, wsw, bo, out);
}

// Round 20
// 231.398 us; speedup vs baseline: 1.4768x; 1.4768x over previous
//
#include <hip/hip_runtime.h>
#include <hip/hip_bf16.h>

#define NN 384
#define CZ 128
#define NH 4
#define NROWS (NN*NN)
#define LN_EPS 1e-5f
#define LOG2E 1.4426950408889634f
#define QSCALE_L2 (0.17677669529663687f * 1.4426950408889634f)  // 1/sqrt(32) * log2(e)

typedef unsigned short u16;
typedef unsigned int   u32;
typedef __attribute__((ext_vector_type(8))) __bf16 bf16x8;
typedef __attribute__((ext_vector_type(16))) float f32x16;
typedef __attribute__((ext_vector_type(2))) float f32x2;

__device__ __forceinline__ float bflo(u32 u) { union { u32 i; float f; } a; a.i = u << 16; return a.f; }
__device__ __forceinline__ float bfhi(u32 u) { union { u32 i; float f; } a; a.i = u & 0xffff0000u; return a.f; }
__device__ __forceinline__ u16 f2bf(float f) {
  union { float f; u32 i; } a; a.f = f;
  u32 r = a.i + 0x7fffu + ((a.i >> 16) & 1u);
  return (u16)(r >> 16);
}
__device__ __forceinline__ u32 cvtpk(float lo, float hi) {
  u32 r; asm("v_cvt_pk_bf16_f32 %0, %1, %2" : "=v"(r) : "v"(lo), "v"(hi)); return r;
}
__device__ __forceinline__ float exp2fast(float x) {
  float r; asm("v_exp_f32 %0, %1" : "=v"(r) : "v"(x)); return r;
}
__device__ __forceinline__ float sigm(float x) {
  return 1.f / (1.f + exp2fast(-x * LOG2E));
}
__device__ __forceinline__ f32x2 pkadd(f32x2 a, f32x2 b) {
  f32x2 d; asm("v_pk_add_f32 %0, %1, %2" : "=v"(d) : "v"(a), "v"(b)); return d;
}

// ---------------- Kernel 0: one-time weight convert + swizzle --------------
__global__ __launch_bounds__(256) void k_wcvt(const float* __restrict__ wq,
    const float* __restrict__ wk, const float* __restrict__ wv,
    const float* __restrict__ wg, const float* __restrict__ wo,
    u16* __restrict__ wsw) {
  int m = blockIdx.x;
  const float* W = (m == 0) ? wq : (m == 1) ? wk : (m == 2) ? wv : (m == 3) ? wg : wo;
  float sc = (m == 0) ? QSCALE_L2 : 1.f;
  u16* dst = wsw + (size_t)m * 16384;
  for (int idx = threadIdx.x; idx < 2048; idx += 256) {
    int e = idx >> 4, s = idx & 15;
    float4 f0 = *(const float4*)&W[e * CZ + s * 8];
    float4 f1 = *(const float4*)&W[e * CZ + s * 8 + 4];
    uint4 st;
    st.x = cvtpk(f0.x * sc, f0.y * sc); st.y = cvtpk(f0.z * sc, f0.w * sc);
    st.z = cvtpk(f1.x * sc, f1.y * sc); st.w = cvtpk(f1.z * sc, f1.w * sc);
    *(uint4*)&dst[e * CZ + (s ^ (e & 15)) * 8] = st;
  }
}

// ---------------- Kernel 1: LayerNorm -> x(bf16, SWIZZLED), pair_bias pbF --
__global__ __launch_bounds__(256) void k_ln(const float* __restrict__ act,
    const float* __restrict__ lnw, const float* __restrict__ lnb,
    const float* __restrict__ w2d, u16* __restrict__ xbf, u16* __restrict__ pbF) {
  int t = threadIdx.x;
  int l32 = t & 31;
  int r = blockIdx.x * 8 + (t >> 5);
  const float4 a = *(const float4*)(act + (size_t)r * CZ + l32 * 4);
  float s = (a.x + a.y) + (a.z + a.w);
  float s2 = (a.x * a.x + a.y * a.y) + (a.z * a.z + a.w * a.w);
  #pragma unroll
  for (int m = 16; m >= 1; m >>= 1) { s += __shfl_xor(s, m, 32); s2 += __shfl_xor(s2, m, 32); }
  float mu = s * (1.0f / CZ);
  float inv = rsqrtf(s2 * (1.0f / CZ) - mu * mu + LN_EPS);
  float4 w = *(const float4*)(lnw + l32 * 4);
  float4 b = *(const float4*)(lnb + l32 * 4);
  float4 xv;
  xv.x = (a.x - mu) * inv * w.x + b.x;
  xv.y = (a.y - mu) * inv * w.y + b.y;
  xv.z = (a.z - mu) * inv * w.z + b.z;
  xv.w = (a.w - mu) * inv * w.w + b.w;
  uint2 st; st.x = cvtpk(xv.x, xv.y); st.y = cvtpk(xv.z, xv.w);
  int scol = ((l32 >> 1) ^ (r & 15)) * 8 + (l32 & 1) * 4;
  *(uint2*)(xbf + (size_t)r * CZ + scol) = st;
  int j = r / NN, k = r - j * NN;
  int t32 = k >> 5, kl = k & 31;
  int gg = (kl >> 2) & 1, rr = (kl & 3) + 4 * (kl >> 3);
  size_t pidx = (size_t)t32 * 12288 + (size_t)j * 32 + gg * 16 + rr;
  #pragma unroll
  for (int h = 0; h < NH; ++h) {
    float4 wd = *(const float4*)(w2d + h * CZ + l32 * 4);
    float p = (xv.x * wd.x + xv.y * wd.y) + (xv.z * wd.z + xv.w * wd.w);
    #pragma unroll
    for (int m = 16; m >= 1; m >>= 1) p += __shfl_xor(p, m, 32);
    if (l32 == 0) pbF[(size_t)h * NROWS + pidx] = f2bf(p * LOG2E);
  }
}

// ---------------- Kernel 2: one-shot MFMA projections ----------------------
// m==2 (v): result transposed through LDS (two half-passes, [64][65] u32
// padded buffer reusing xl) so vT writes are fully coalesced uint4 stores.
__global__ __launch_bounds__(256) void k_projf(const u16* __restrict__ x,
    const u16* __restrict__ wsw, const float* __restrict__ bg,
    u16* __restrict__ qb, u16* __restrict__ kb,
    u16* __restrict__ vT, u16* __restrict__ gb) {
  __shared__ __align__(16) u16 wl[128][128];  // 32 KB
  __shared__ __align__(16) u16 xl[128][128];  // 32 KB
  int t = threadIdx.x;
  int lane = t & 63, wid = t >> 6;
  int jl = lane & 31, g = lane >> 5;
  int m = blockIdx.y;
  size_t row0 = (size_t)blockIdx.x * 128;
  {
    const uint4* wsrc = (const uint4*)(wsw + (size_t)m * 16384);
    const uint4* xsrc = (const uint4*)(x + row0 * CZ);
    uint4* wd = (uint4*)wl;
    uint4* xd = (uint4*)xl;
    #pragma unroll
    for (int p = 0; p < 8; ++p) {
      wd[t + p * 256] = wsrc[t + p * 256];
      xd[t + p * 256] = xsrc[t + p * 256];
    }
  }
  __syncthreads();
  int rf = (wid & 1) * 64, ef = (wid >> 1) * 64;
  f32x16 acc[2][2];
  #pragma unroll
  for (int a = 0; a < 2; ++a)
    #pragma unroll
    for (int b = 0; b < 2; ++b)
      #pragma unroll
      for (int i = 0; i < 16; ++i) acc[a][b][i] = 0.f;

  #pragma unroll
  for (int ks = 0; ks < 8; ++ks) {
    bf16x8 xa[2], wf[2];
    #pragma unroll
    for (int a = 0; a < 2; ++a) {
      int r = rf + a * 32 + jl;
      xa[a] = *(const bf16x8*)&xl[r][((2 * ks + g) ^ (r & 15)) * 8];
    }
    #pragma unroll
    for (int b = 0; b < 2; ++b) {
      int e = ef + b * 32 + jl;
      wf[b] = *(const bf16x8*)&wl[e][((2 * ks + g) ^ (e & 15)) * 8];
    }
    if (m == 2) {
      #pragma unroll
      for (int a = 0; a < 2; ++a)
        #pragma unroll
        for (int b = 0; b < 2; ++b)
          acc[a][b] = __builtin_amdgcn_mfma_f32_32x32x16_bf16(xa[a], wf[b], acc[a][b], 0, 0, 0);
    } else {
      #pragma unroll
      for (int a = 0; a < 2; ++a)
        #pragma unroll
        for (int b = 0; b < 2; ++b)
          acc[a][b] = __builtin_amdgcn_mfma_f32_32x32x16_bf16(wf[b], xa[a], acc[a][b], 0, 0, 0);
    }
  }

  if (m == 2) {  // v: C lane = e, regs = token row -> LDS transpose -> vT
    __syncthreads();  // compute done reading xl; reuse as [64][65] u32
    u32* tb = (u32*)xl;
    #pragma unroll
    for (int half = 0; half < 2; ++half) {
      if ((wid >> 1) == half) {
        #pragma unroll
        for (int a = 0; a < 2; ++a)
          #pragma unroll
          for (int b = 0; b < 2; ++b) {
            int e_loc = b * 32 + jl;
            #pragma unroll
            for (int rr = 0; rr < 4; ++rr) {
              int tok = rf + a * 32 + 8 * rr + 4 * g;  // multiple of 4
              tb[e_loc * 65 + (tok >> 1)]     = cvtpk(acc[a][b][4 * rr + 0], acc[a][b][4 * rr + 1]);
              tb[e_loc * 65 + (tok >> 1) + 1] = cvtpk(acc[a][b][4 * rr + 2], acc[a][b][4 * rr + 3]);
            }
          }
      }
      __syncthreads();
      #pragma unroll
      for (int it = 0; it < 4; ++it) {
        int idx = t + it * 256;         // 1024 chunks of 8 tokens
        int e_loc = idx >> 4, cc = idx & 15;
        uint4 st;
        st.x = tb[e_loc * 65 + cc * 4 + 0];
        st.y = tb[e_loc * 65 + cc * 4 + 1];
        st.z = tb[e_loc * 65 + cc * 4 + 2];
        st.w = tb[e_loc * 65 + cc * 4 + 3];
        *(uint4*)&vT[(size_t)(half * 64 + e_loc) * NROWS + row0 + cc * 8] = st;
      }
      __syncthreads();
    }
  } else {  // q/k/g: C lane = row, regs = e -> row-major store
    u16* ob = (m == 0) ? qb : (m == 1) ? kb : gb;
    #pragma unroll
    for (int a = 0; a < 2; ++a) {
      size_t row = row0 + rf + a * 32 + jl;
      #pragma unroll
      for (int b = 0; b < 2; ++b) {
        u16* dst = ob + row * CZ + ef + b * 32 + 4 * g;
        #pragma unroll
        for (int rr = 0; rr < 4; ++rr) {
          float v0 = acc[a][b][4 * rr + 0], v1 = acc[a][b][4 * rr + 1];
          float v2 = acc[a][b][4 * rr + 2], v3 = acc[a][b][4 * rr + 3];
          if (m == 3) {
            float4 bv = *(const float4*)&bg[ef + b * 32 + 8 * rr + 4 * g];
            v0 = sigm(v0 + bv.x); v1 = sigm(v1 + bv.y);
            v2 = sigm(v2 + bv.z); v3 = sigm(v3 + bv.w);
          }
          uint2 st; st.x = cvtpk(v0, v1); st.y = cvtpk(v2, v3);
          *(uint2*)(dst + 8 * rr) = st;
        }
      }
    }
  }
}

// ---------------- Kernel 3: MFMA attention, KVBLK=64, no-max softmax, ------
// pb 2-deep prefetch (ping-pong uint4 sets; iter kt prefetches kt+1).
template<bool MASKED>
__device__ __forceinline__ void attn_core(const u16* ks, const u16* vs,
    const u16* pbw, const float* mrow4, int jl, int g,
    bf16x8 qf0, bf16x8 qf1, f32x16& oacc, float& lrun,
    uint4 pbA0, uint4 pbA1, uint4 pbA2, uint4 pbA3) {
  uint4 pbB0, pbB1, pbB2, pbB3;

#define ATTN_STEP(CUR, NXT, KT)                                                \
  {                                                                            \
    const int k0 = (KT) * 64;                                                  \
    const int k1 = k0 + 32;                                                    \
    if ((KT) + 1 < 6) {                                                        \
      pb##NXT##0 = *(const uint4*)(pbw + (size_t)(2 * ((KT) + 1)) * 12288);    \
      pb##NXT##1 = *(const uint4*)(pbw + (size_t)(2 * ((KT) + 1)) * 12288 + 8);\
      pb##NXT##2 = *(const uint4*)(pbw + (size_t)(2 * ((KT) + 1) + 1) * 12288);\
      pb##NXT##3 = *(const uint4*)(pbw + (size_t)(2 * ((KT) + 1) + 1) * 12288 + 8);\
    }                                                                          \
    bf16x8 ka0a = *(const bf16x8*)&ks[(k0 + jl) * 40 + 8 * g];                 \
    bf16x8 ka1a = *(const bf16x8*)&ks[(k0 + jl) * 40 + 8 * g + 16];            \
    bf16x8 ka0b = *(const bf16x8*)&ks[(k1 + jl) * 40 + 8 * g];                 \
    bf16x8 ka1b = *(const bf16x8*)&ks[(k1 + jl) * 40 + 8 * g + 16];            \
    bf16x8 va0a = *(const bf16x8*)&vs[jl * 392 + k0 + 8 * g];                  \
    bf16x8 va1a = *(const bf16x8*)&vs[jl * 392 + k0 + 16 + 8 * g];             \
    bf16x8 va0b = *(const bf16x8*)&vs[jl * 392 + k1 + 8 * g];                  \
    bf16x8 va1b = *(const bf16x8*)&vs[jl * 392 + k1 + 16 + 8 * g];             \
    float pva[16], pvb[16];                                                    \
    pva[0]=bflo((pb##CUR##0).x); pva[1]=bfhi((pb##CUR##0).x);                  \
    pva[2]=bflo((pb##CUR##0).y); pva[3]=bfhi((pb##CUR##0).y);                  \
    pva[4]=bflo((pb##CUR##0).z); pva[5]=bfhi((pb##CUR##0).z);                  \
    pva[6]=bflo((pb##CUR##0).w); pva[7]=bfhi((pb##CUR##0).w);                  \
    pva[8]=bflo((pb##CUR##1).x); pva[9]=bfhi((pb##CUR##1).x);                  \
    pva[10]=bflo((pb##CUR##1).y); pva[11]=bfhi((pb##CUR##1).y);                \
    pva[12]=bflo((pb##CUR##1).z); pva[13]=bfhi((pb##CUR##1).z);                \
    pva[14]=bflo((pb##CUR##1).w); pva[15]=bfhi((pb##CUR##1).w);                \
    pvb[0]=bflo((pb##CUR##2).x); pvb[1]=bfhi((pb##CUR##2).x);                  \
    pvb[2]=bflo((pb##CUR##2).y); pvb[3]=bfhi((pb##CUR##2).y);                  \
    pvb[4]=bflo((pb##CUR##2).z); pvb[5]=bfhi((pb##CUR##2).z);                  \
    pvb[6]=bflo((pb##CUR##2).w); pvb[7]=bfhi((pb##CUR##2).w);                  \
    pvb[8]=bflo((pb##CUR##3).x); pvb[9]=bfhi((pb##CUR##3).x);                  \
    pvb[10]=bflo((pb##CUR##3).y); pvb[11]=bfhi((pb##CUR##3).y);                \
    pvb[12]=bflo((pb##CUR##3).z); pvb[13]=bfhi((pb##CUR##3).z);                \
    pvb[14]=bflo((pb##CUR##3).w); pvb[15]=bfhi((pb##CUR##3).w);                \
    f32x16 sacA, sacB;                                                         \
    _Pragma("unroll")                                                          \
    for (int r = 0; r < 16; ++r) { sacA[r] = 0.f; sacB[r] = 0.f; }             \
    __builtin_amdgcn_s_setprio(1);                                             \
    sacA = __builtin_amdgcn_mfma_f32_32x32x16_bf16(ka0a, qf0, sacA, 0, 0, 0);  \
    sacB = __builtin_amdgcn_mfma_f32_32x32x16_bf16(ka0b, qf0, sacB, 0, 0, 0);  \
    sacA = __builtin_amdgcn_mfma_f32_32x32x16_bf16(ka1a, qf1, sacA, 0, 0, 0);  \
    sacB = __builtin_amdgcn_mfma_f32_32x32x16_bf16(ka1b, qf1, sacB, 0, 0, 0);  \
    __builtin_amdgcn_s_setprio(0);                                             \
    f32x2 sa[8], sb[8];                                                        \
    _Pragma("unroll")                                                          \
    for (int rr = 0; rr < 4; ++rr) {                                           \
      sa[2 * rr + 0] = pkadd(f32x2{sacA[4 * rr + 0], sacA[4 * rr + 1]},        \
                             f32x2{pva[4 * rr + 0], pva[4 * rr + 1]});         \
      sa[2 * rr + 1] = pkadd(f32x2{sacA[4 * rr + 2], sacA[4 * rr + 3]},        \
                             f32x2{pva[4 * rr + 2], pva[4 * rr + 3]});         \
      sb[2 * rr + 0] = pkadd(f32x2{sacB[4 * rr + 0], sacB[4 * rr + 1]},        \
                             f32x2{pvb[4 * rr + 0], pvb[4 * rr + 1]});         \
      sb[2 * rr + 1] = pkadd(f32x2{sacB[4 * rr + 2], sacB[4 * rr + 3]},        \
                             f32x2{pvb[4 * rr + 2], pvb[4 * rr + 3]});         \
    }                                                                          \
    if (MASKED) {                                                              \
      _Pragma("unroll")                                                        \
      for (int m4 = 0; m4 < 4; ++m4) {                                         \
        float4 ma = *(const float4*)(mrow4 + k0 + 8 * m4);                     \
        float4 mb = *(const float4*)(mrow4 + k1 + 8 * m4);                     \
        sa[2 * m4 + 0] = pkadd(sa[2 * m4 + 0],                                 \
            f32x2{(ma.x - 1.f) * (1e9f * LOG2E), (ma.y - 1.f) * (1e9f * LOG2E)});\
        sa[2 * m4 + 1] = pkadd(sa[2 * m4 + 1],                                 \
            f32x2{(ma.z - 1.f) * (1e9f * LOG2E), (ma.w - 1.f) * (1e9f * LOG2E)});\
        sb[2 * m4 + 0] = pkadd(sb[2 * m4 + 0],                                 \
            f32x2{(mb.x - 1.f) * (1e9f * LOG2E), (mb.y - 1.f) * (1e9f * LOG2E)});\
        sb[2 * m4 + 1] = pkadd(sb[2 * m4 + 1],                                 \
            f32x2{(mb.z - 1.f) * (1e9f * LOG2E), (mb.w - 1.f) * (1e9f * LOG2E)});\
      }                                                                        \
    }                                                                          \
    f32x2 p2a[8], p2b[8];                                                      \
    _Pragma("unroll")                                                          \
    for (int p8 = 0; p8 < 8; ++p8) {                                           \
      p2a[p8] = f32x2{exp2fast(sa[p8][0]), exp2fast(sa[p8][1])};               \
      p2b[p8] = f32x2{exp2fast(sb[p8][0]), exp2fast(sb[p8][1])};               \
    }                                                                          \
    f32x2 qa0 = pkadd(pkadd(p2a[0], p2a[1]), pkadd(p2a[2], p2a[3]));           \
    f32x2 qa1 = pkadd(pkadd(p2a[4], p2a[5]), pkadd(p2a[6], p2a[7]));           \
    f32x2 qb0 = pkadd(pkadd(p2b[0], p2b[1]), pkadd(p2b[2], p2b[3]));           \
    f32x2 qb1 = pkadd(pkadd(p2b[4], p2b[5]), pkadd(p2b[6], p2b[7]));           \
    f32x2 qt = pkadd(pkadd(qa0, qa1), pkadd(qb0, qb1));                        \
    lrun += qt[0] + qt[1];                                                     \
    u32 Aa = cvtpk(p2a[0][0], p2a[0][1]), Ab = cvtpk(p2a[1][0], p2a[1][1]);    \
    u32 Ba = cvtpk(p2a[2][0], p2a[2][1]), Bb = cvtpk(p2a[3][0], p2a[3][1]);    \
    u32 Ca = cvtpk(p2a[4][0], p2a[4][1]), Cb = cvtpk(p2a[5][0], p2a[5][1]);    \
    u32 Da = cvtpk(p2a[6][0], p2a[6][1]), Db = cvtpk(p2a[7][0], p2a[7][1]);    \
    u32 Ea = cvtpk(p2b[0][0], p2b[0][1]), Eb = cvtpk(p2b[1][0], p2b[1][1]);    \
    u32 Fa = cvtpk(p2b[2][0], p2b[2][1]), Fb = cvtpk(p2b[3][0], p2b[3][1]);    \
    u32 Ga = cvtpk(p2b[4][0], p2b[4][1]), Gb = cvtpk(p2b[5][0], p2b[5][1]);    \
    u32 Ha = cvtpk(p2b[6][0], p2b[6][1]), Hb = cvtpk(p2b[7][0], p2b[7][1]);    \
    auto r0 = __builtin_amdgcn_permlane32_swap(Aa, Ba, false, false);          \
    auto r1 = __builtin_amdgcn_permlane32_swap(Ab, Bb, false, false);          \
    auto r2 = __builtin_amdgcn_permlane32_swap(Ca, Da, false, false);          \
    auto r3 = __builtin_amdgcn_permlane32_swap(Cb, Db, false, false);          \
    auto r4 = __builtin_amdgcn_permlane32_swap(Ea, Fa, false, false);          \
    auto r5 = __builtin_amdgcn_permlane32_swap(Eb, Fb, false, false);          \
    auto r6 = __builtin_amdgcn_permlane32_swap(Ga, Ha, false, false);          \
    auto r7 = __builtin_amdgcn_permlane32_swap(Gb, Hb, false, false);          \
    union { u32 w[4]; bf16x8 v; } b0, b1, b2, b3;                              \
    b0.w[0] = r0[0]; b0.w[1] = r1[0]; b0.w[2] = r0[1]; b0.w[3] = r1[1];        \
    b1.w[0] = r2[0]; b1.w[1] = r3[0]; b1.w[2] = r2[1]; b1.w[3] = r3[1];        \
    b2.w[0] = r4[0]; b2.w[1] = r5[0]; b2.w[2] = r4[1]; b2.w[3] = r5[1];        \
    b3.w[0] = r6[0]; b3.w[1] = r7[0]; b3.w[2] = r6[1]; b3.w[3] = r7[1];        \
    __builtin_amdgcn_s_setprio(1);                                             \
    oacc = __builtin_amdgcn_mfma_f32_32x32x16_bf16(va0a, b0.v, oacc, 0, 0, 0); \
    oacc = __builtin_amdgcn_mfma_f32_32x32x16_bf16(va1a, b1.v, oacc, 0, 0, 0); \
    oacc = __builtin_amdgcn_mfma_f32_32x32x16_bf16(va0b, b2.v, oacc, 0, 0, 0); \
    oacc = __builtin_amdgcn_mfma_f32_32x32x16_bf16(va1b, b3.v, oacc, 0, 0, 0); \
    __builtin_amdgcn_s_setprio(0);                                             \
  }

  ATTN_STEP(A, B, 0); ATTN_STEP(B, A, 1); ATTN_STEP(A, B, 2);
  ATTN_STEP(B, A, 3); ATTN_STEP(A, B, 4); ATTN_STEP(B, A, 5);
#undef ATTN_STEP
}

__global__ __launch_bounds__(768) void k_attn(const u16* __restrict__ q,
    const u16* __restrict__ kmat, const u16* __restrict__ vT,
    const u16* __restrict__ pbF, const float* __restrict__ mask,
    const u16* __restrict__ gmat, u16* __restrict__ o) {
  __shared__ __align__(16) u16 ks[384 * 40];  // K rows padded to 40 bf16
  __shared__ __align__(16) u16 vs[32 * 392];  // V^T rows padded to 392 bf16
  int i = blockIdx.x, h = blockIdx.y;
  int t = threadIdx.x;
  int lane = t & 63, wid = t >> 6;  // wid 0..11
  int jl = lane & 31, g = lane >> 5;
  int j = wid * 32 + jl;
  size_t base = ((size_t)i * NN) * CZ + h * 32;
  // issue per-wave long-latency loads BEFORE staging (overlap)
  const u16* pbw = pbF + (size_t)h * NROWS + (size_t)j * 32 + g * 16;
  uint4 pbA0 = *(const uint4*)(pbw);
  uint4 pbA1 = *(const uint4*)(pbw + 8);
  uint4 pbA2 = *(const uint4*)(pbw + 12288);
  uint4 pbA3 = *(const uint4*)(pbw + 12288 + 8);
  const u16* qp = q + base + (size_t)j * CZ + g * 8;
  bf16x8 qf0 = *(const bf16x8*)qp;
  bf16x8 qf1 = *(const bf16x8*)(qp + 16);
  {
    const u16* src = kmat + base;
    for (int idx = t; idx < 1536; idx += 768) {
      int row = idx >> 2, c = idx & 3;
      *(uint4*)&ks[row * 40 + c * 8] = *(const uint4*)(src + (size_t)row * CZ + c * 8);
    }
    const u16* vsrc = vT + (size_t)(h * 32) * NROWS + (size_t)i * NN;
    for (int idx = t; idx < 1536; idx += 768) {
      int d = idx / 48, c = idx % 48;
      *(uint4*)&vs[d * 392 + c * 8] = *(const uint4*)(vsrc + (size_t)d * NROWS + c * 8);
    }
  }
  const float* mrow = mask + (size_t)i * NN;
  bool m1 = true;
  #pragma unroll
  for (int c = 0; c < 6; ++c) m1 &= (mrow[lane + 64 * c] == 1.f);
  bool nomask = __all(m1);
  __syncthreads();

  f32x16 oacc;
  #pragma unroll
  for (int r = 0; r < 16; ++r) oacc[r] = 0.f;
  float lrun = 0.f;
  if (nomask) attn_core<false>(ks, vs, pbw, mrow + 4 * g, jl, g, qf0, qf1, oacc, lrun,
                               pbA0, pbA1, pbA2, pbA3);
  else        attn_core<true >(ks, vs, pbw, mrow + 4 * g, jl, g, qf0, qf1, oacc, lrun,
                               pbA0, pbA1, pbA2, pbA3);

  float lt = lrun + __shfl_xor(lrun, 32, 64);
  float inv = 1.f / lt;
  const u16* gp = gmat + (size_t)(i * NN + j) * CZ + h * 32 + 4 * g;
  u16* dst = o + (size_t)(i * NN + j) * CZ + h * 32 + 4 * g;
  #pragma unroll
  for (int q4 = 0; q4 < 4; ++q4) {
    uint2 gu = *(const uint2*)(gp + 8 * q4);
    uint2 st;
    st.x = cvtpk(oacc[4 * q4 + 0] * inv * bflo(gu.x), oacc[4 * q4 + 1] * inv * bfhi(gu.x));
    st.y = cvtpk(oacc[4 * q4 + 2] * inv * bflo(gu.y), oacc[4 * q4 + 3] * inv * bfhi(gu.y));
    *(uint2*)(dst + 8 * q4) = st;
  }
}

// ---------------- Kernel 4: MFMA out = t @ wo^T + bo  (fp32 out) -----------
__global__ __launch_bounds__(256) void k_out(const u16* __restrict__ tin,
    const u16* __restrict__ wsw, const float* __restrict__ bo,
    float* __restrict__ out) {
  __shared__ __align__(16) u16 wols[128][128];  // 32 KB
  __shared__ __align__(16) u16 tls[128][128];   // 32 KB
  int t = threadIdx.x;
  int lane = t & 63, wid = t >> 6, jl = lane & 31, gg = lane >> 5;
  size_t row0 = (size_t)blockIdx.x * 128;
  {
    const uint4* wsrc = (const uint4*)(wsw + (size_t)4 * 16384);  // wo slot
    uint4* wd = (uint4*)wols;
    #pragma unroll
    for (int p = 0; p < 8; ++p) wd[t + p * 256] = wsrc[t + p * 256];
  }
  #pragma unroll
  for (int it = 0; it < 8; ++it) {
    int idx = t + it * 256; int r = idx >> 4, s = idx & 15;
    uint4 uo = *(const uint4*)(tin + (row0 + r) * CZ + s * 8);
    *(uint4*)&tls[r][(s ^ (r & 15)) * 8] = uo;
  }
  __syncthreads();
  f32x16 acc[4];
  #pragma unroll
  for (int cf = 0; cf < 4; ++cf)
    #pragma unroll
    for (int i = 0; i < 16; ++i) acc[cf][i] = 0.f;
  #pragma unroll
  for (int ks = 0; ks < 8; ++ks) {
    int r = wid * 32 + jl;
    bf16x8 tf = *(const bf16x8*)&tls[r][((2 * ks + gg) ^ (r & 15)) * 8];
    #pragma unroll
    for (int cf = 0; cf < 4; ++cf) {
      int c = cf * 32 + jl;
      bf16x8 wf = *(const bf16x8*)&wols[c][((2 * ks + gg) ^ (c & 15)) * 8];
      acc[cf] = __builtin_amdgcn_mfma_f32_32x32x16_bf16(wf, tf, acc[cf], 0, 0, 0);
    }
  }
  size_t row = row0 + wid * 32 + jl;
  #pragma unroll
  for (int cf = 0; cf < 4; ++cf)
    #pragma unroll
    for (int rr = 0; rr < 4; ++rr) {
      int c = cf * 32 + 8 * rr + 4 * gg;
      float4 bv = *(const float4*)&bo[c];
      float4 v;
      v.x = acc[cf][4 * rr + 0] + bv.x; v.y = acc[cf][4 * rr + 1] + bv.y;
      v.z = acc[cf][4 * rr + 2] + bv.z; v.w = acc[cf][4 * rr + 3] + bv.w;
      *(float4*)&out[row * CZ + c] = v;
    }
}

extern "C" void kernel_launch(void* const* d_in, const int* in_sizes, int n_in,
                              void* d_out, int out_size, void* d_ws, size_t ws_size,
                              hipStream_t stream) {
  const float* act  = (const float*)d_in[0];
  const float* mask = (const float*)d_in[1];
  const float* ln_w = (const float*)d_in[2];
  const float* ln_b = (const float*)d_in[3];
  const float* w2d  = (const float*)d_in[4];
  const float* wq   = (const float*)d_in[5];
  const float* wk   = (const float*)d_in[6];
  const float* wv   = (const float*)d_in[7];
  const float* wg   = (const float*)d_in[8];
  const float* bg   = (const float*)d_in[9];
  const float* wo   = (const float*)d_in[10];
  const float* bo   = (const float*)d_in[11];
  float* out = (float*)d_out;

  char* ws = (char*)d_ws;
  const size_t sz = (size_t)NROWS * CZ * 2;
  u16* xbf = (u16*)ws;
  u16* qb  = (u16*)(ws + 1 * sz);
  u16* kb  = (u16*)(ws + 2 * sz);
  u16* vTb = (u16*)(ws + 3 * sz);
  u16* gb  = (u16*)(ws + 4 * sz);
  u16* ob  = (u16*)(ws + 5 * sz);   // holds t = (o/l)*g after k_attn
  u16* pbf = (u16*)(ws + 6 * sz);   // NH*NROWS u16 = 1.18 MB
  u16* wsw = (u16*)(ws + 6 * sz + (2 << 20));  // 5 x 32 KB

  k_wcvt<<<5, 256, 0, stream>>>(wq, wk, wv, wg, wo, wsw);
  k_ln<<<NROWS / 8, 256, 0, stream>>>(act, ln_w, ln_b, w2d, xbf, pbf);
  dim3 gp(NROWS / 128, 4);
  k_projf<<<gp, 256, 0, stream>>>(xbf, wsw, bg, qb, kb, vTb, gb);
  dim3 ga(NN, NH);
  k_attn<<<ga, 768, 0, stream>>>(qb, kb, vTb, pbf, mask, gb, ob);
  k_out<<<NROWS / 128, 256, 0, stream>>>(ob, wsw, bo, out);
}